// Round 10
// baseline (950.863 us; speedup 1.0000x reference)
//
#include <hip/hip_runtime.h>

// ---- problem constants (from reference) ----
#define TSTEPS 256
#define NPOP 4
#define NI 8
#define NO 4
#define NF 28            // NI + 2*NR + NO
#define RANDN 512
#define NBATCH 64
#define NSTATES (NPOP*RANDN)   // 2048
#define ALPHA 0.2f             // DT/TAU
#define ONEMA 0.8f
#define SPT 8                  // states per thread (64 threads/population)
#define CHUNK 8                // timesteps per ext-kernel block (2048 blocks)

#define GROUPS 2               // batches per block (dual-chain main kernel)
#define GTHREADS 256           // threads per group (4 waves)
#define DTHREADS (GROUPS*GTHREADS)

__device__ __forceinline__ float vexp2(float x) { return __builtin_amdgcn_exp2f(x); }
__device__ __forceinline__ float vrcp(float x)  { return __builtin_amdgcn_rcpf(x); }

// tanh(x) = 1 - 2/(e^{2x}+1)
__device__ __forceinline__ float ftanh(float x) {
    float t = vexp2(x * 2.885390081777927f);
    return __builtin_fmaf(-2.0f, vrcp(t + 1.0f), 1.0f);
}

template<int CTRL, int RM, int BM>
__device__ __forceinline__ float dpp_add(float x) {
    int v = __builtin_amdgcn_update_dpp(0, __float_as_int(x), CTRL, RM, BM, true);
    return x + __int_as_float(v);
}

// full wave64 sum -> valid in lane 63
__device__ __forceinline__ float wave_red_sum(float x) {
    x = dpp_add<0x111, 0xf, 0xf>(x);  // row_shr:1
    x = dpp_add<0x112, 0xf, 0xf>(x);  // row_shr:2
    x = dpp_add<0x114, 0xf, 0xf>(x);  // row_shr:4
    x = dpp_add<0x118, 0xf, 0xf>(x);  // row_shr:8
    x = dpp_add<0x142, 0xa, 0xf>(x);  // row_bcast:15 -> rows 1,3
    x = dpp_add<0x143, 0xc, 0xf>(x);  // row_bcast:31 -> rows 2,3
    return x;
}

// sum within each 4-lane group -> valid at lanes 4g+3
__device__ __forceinline__ float red4(float x) {
    x = dpp_add<0x111, 0xf, 0xf>(x);
    x = dpp_add<0x112, 0xf, 0xf>(x);
    return x;
}

// barrier with LDS-only ordering (vmcnt stays in flight across it)
__device__ __forceinline__ void lds_barrier() {
    asm volatile("s_waitcnt lgkmcnt(0)\n\ts_barrier" ::: "memory");
}

__device__ __forceinline__ float readlane_f(float x, int l) {
    return __uint_as_float(__builtin_amdgcn_readlane(__float_as_uint(x), l));
}

// =====================================================================
// Pre-kernel: ext[b][t][s] = ALPHA*( noise_rec[b][t][s] + I[s,:]·u[b][t,:] )
// 2048 blocks, BW-bound.
// =====================================================================
__global__ __launch_bounds__(256, 4) void ext_kernel(
    const float* __restrict__ u,      // [B][T][NI]
    const float* __restrict__ mu,     // [NPOP][NF]
    const float* __restrict__ C,      // [NPOP][NF][NF]
    const float* __restrict__ nl,     // [NPOP][RANDN][NF]
    const float* __restrict__ nrec,   // [B][T][NSTATES]
    float* __restrict__ ext)          // [B][T][NSTATES]
{
    __shared__ float c_lds[NPOP * NF * NF];
    __shared__ float u_sh[CHUNK * NI];

    const int tid = threadIdx.x;
    const int b   = blockIdx.x >> 5;                 // 32 chunks per batch
    const int tch = (blockIdx.x & 31) * CHUNK;
    const int p   = tid >> 6;
    const int s0  = tid * SPT;

    {
        const float4* src = (const float4*)C;
        float4* dst = (float4*)c_lds;
        #pragma unroll
        for (int i = 0; i < 4; ++i) {
            int idx = tid + i * 256;
            if (idx < NPOP * NF * NF / 4) dst[idx] = src[idx];
        }
    }
    if (tid < CHUNK * NI / 4)
        ((float4*)u_sh)[tid] = ((const float4*)(u + (size_t)b * TSTEPS * NI + tch * NI))[tid];
    __syncthreads();

    // WI[k][i] = ALPHA * I-loading column i for state s0+k
    float WI[SPT][8];
    #pragma unroll
    for (int c = 0; c < 8; ++c) {
        float m = mu[p * NF + c];
        #pragma unroll
        for (int k = 0; k < SPT; ++k) WI[k][c] = m;
    }
    #pragma unroll
    for (int pr = 0; pr < 4; ++pr) {
        float nlr[2][NF];
        #pragma unroll
        for (int kk = 0; kk < 2; ++kk) {
            const float4* src = (const float4*)(nl + (size_t)(s0 + pr * 2 + kk) * NF);
            #pragma unroll
            for (int q = 0; q < 7; ++q) {
                float4 v = src[q];
                nlr[kk][q*4+0] = v.x; nlr[kk][q*4+1] = v.y;
                nlr[kk][q*4+2] = v.z; nlr[kk][q*4+3] = v.w;
            }
        }
        #pragma unroll
        for (int f = 0; f < 8; ++f) {
            const float4* cr = (const float4*)&c_lds[(p * NF + f) * NF];
            float crow[NF];
            #pragma unroll
            for (int q = 0; q < 7; ++q) {
                float4 v = cr[q];
                crow[q*4+0] = v.x; crow[q*4+1] = v.y;
                crow[q*4+2] = v.z; crow[q*4+3] = v.w;
            }
            #pragma unroll
            for (int kk = 0; kk < 2; ++kk) {
                float acc = WI[pr*2+kk][f];
                #pragma unroll
                for (int ss = 0; ss < NF; ++ss)
                    acc = __builtin_fmaf(crow[ss], nlr[kk][ss], acc);
                WI[pr*2+kk][f] = acc;
            }
        }
    }
    #pragma unroll
    for (int k = 0; k < SPT; ++k)
        #pragma unroll
        for (int c = 0; c < 8; ++c) WI[k][c] *= ALPHA;

    const size_t rowq = NSTATES / 4;
    const float4* nb = (const float4*)nrec + ((size_t)b * TSTEPS + tch) * rowq + tid * 2;
    float4*       eb = (float4*)ext        + ((size_t)b * TSTEPS + tch) * rowq + tid * 2;

    #pragma unroll 2
    for (int j = 0; j < CHUNK; ++j) {
        float4 m0 = nb[(size_t)j * rowq];
        float4 m1 = nb[(size_t)j * rowq + 1];
        float ut[8];
        #pragma unroll
        for (int i = 0; i < 8; ++i) ut[i] = u_sh[j * NI + i];
        float nn[8] = {m0.x, m0.y, m0.z, m0.w, m1.x, m1.y, m1.z, m1.w};
        float ex[8];
        #pragma unroll
        for (int k = 0; k < SPT; ++k) {
            float a = ALPHA * nn[k];
            #pragma unroll
            for (int i = 0; i < 8; ++i) a = __builtin_fmaf(ut[i], WI[k][i], a);
            ex[k] = a;
        }
        eb[(size_t)j * rowq]     = float4{ex[0], ex[1], ex[2], ex[3]};
        eb[(size_t)j * rowq + 1] = float4{ex[4], ex[5], ex[6], ex[7]};
    }
}

// =====================================================================
// Dual-chain sequential kernel: 2 batches per block, 2 waves/SIMD with
// INDEPENDENT recurrence chains filling each other's stalls.
// __launch_bounds__(512, 1): 1 block/CU -> 2 waves/SIMD -> 256-VGPR budget.
// =====================================================================
__global__ __launch_bounds__(DTHREADS, 1)
void rnn_dual(
    const float* __restrict__ G,      // [NPOP]
    const float* __restrict__ mu,     // [NPOP][NF]
    const float* __restrict__ C,      // [NPOP][NF][NF]
    const float* __restrict__ h0,     // [NPOP][RANDN]
    const float* __restrict__ nl,     // [NPOP][RANDN][NF]
    const float* __restrict__ ext,    // [B][T][NSTATES]  (precomputed)
    float* __restrict__ y)            // [B][T+1][NO]
{
    __shared__ float c_lds[NPOP * NF * NF];
    __shared__ float mu_lds[NPOP * NF];
    __shared__ __align__(16) float part[GROUPS][2][4][8];
    __shared__ __align__(16) float ybuf[GROUPS][TSTEPS + 1][4][4];

    const int tid   = threadIdx.x;
    const int lane  = tid & 63;
    const int wid   = tid >> 6;
    const int g     = wid >> 2;              // group = batch within block
    const int gw    = wid & 3;               // wave within group (= population)
    const int gm    = tid & (GTHREADS - 1);  // slot 0..255
    const int p     = gw;
    const int s0    = gm * SPT;
    const int batch = blockIdx.x * GROUPS + g;

    {
        const float4* s4 = (const float4*)C;
        float4* dst = (float4*)c_lds;
        if (tid < NPOP * NF * NF / 4) dst[tid] = s4[tid];
        int idx2 = tid + DTHREADS;
        if (idx2 < NPOP * NF * NF / 4) dst[idx2] = s4[idx2];
    }
    if (tid < NPOP * NF) mu_lds[tid] = mu[tid];

    float w_p;
    {
        float g0 = G[0], g1 = G[1], g2 = G[2], g3 = G[3];
        float mx = fmaxf(fmaxf(g0, g1), fmaxf(g2, g3));
        const float L2E = 1.4426950408889634f;
        float e0 = vexp2((g0 - mx) * L2E), e1 = vexp2((g1 - mx) * L2E);
        float e2 = vexp2((g2 - mx) * L2E), e3 = vexp2((g3 - mx) * L2E);
        float inv = vrcp(e0 + e1 + e2 + e3);
        float ap = (p == 0) ? e0 : (p == 1) ? e1 : (p == 2) ? e2 : e3;
        w_p = ap * inv * (1.0f / (float)RANDN);
    }
    __syncthreads();

    // ---- loading rows (batch-independent; both groups compute same W) ----
    float WU[SPT][8];          // alpha*U (f=8..15)
    float WV[SPT][8];          // w*V     (f=16..23)
    float WO[SPT][4];          // w*O     (f=24..27)

    #pragma unroll
    for (int pr = 0; pr < 4; ++pr) {       // 2 states at a time
        float nlr[2][NF];
        #pragma unroll
        for (int kk = 0; kk < 2; ++kk) {
            const float4* s4 = (const float4*)(nl + (size_t)(s0 + pr * 2 + kk) * NF);
            #pragma unroll
            for (int q = 0; q < 7; ++q) {
                float4 v = s4[q];
                nlr[kk][q*4+0] = v.x; nlr[kk][q*4+1] = v.y;
                nlr[kk][q*4+2] = v.z; nlr[kk][q*4+3] = v.w;
            }
        }
        #pragma unroll
        for (int f = 8; f < NF; ++f) {
            const float4* cr = (const float4*)&c_lds[(p * NF + f) * NF];
            float crow[NF];
            #pragma unroll
            for (int q = 0; q < 7; ++q) {
                float4 v = cr[q];
                crow[q*4+0] = v.x; crow[q*4+1] = v.y;
                crow[q*4+2] = v.z; crow[q*4+3] = v.w;
            }
            #pragma unroll
            for (int kk = 0; kk < 2; ++kk) {
                int k = pr * 2 + kk;
                float acc = mu_lds[p * NF + f];
                #pragma unroll
                for (int ss = 0; ss < NF; ++ss)
                    acc = __builtin_fmaf(crow[ss], nlr[kk][ss], acc);
                if (f < 16)      WU[k][f - 8]  = acc;
                else if (f < 24) WV[k][f - 16] = acc;
                else             WO[k][f - 24] = acc;
            }
        }
    }
    #pragma unroll
    for (int k = 0; k < SPT; ++k) {
        #pragma unroll
        for (int c = 0; c < 8; ++c) { WU[k][c] *= ALPHA; WV[k][c] *= w_p; }
        #pragma unroll
        for (int c = 0; c < 4; ++c) WO[k][c] *= w_p;
    }

    float h[SPT];
    {
        const float4* hp = (const float4*)(h0 + s0);
        float4 v0 = hp[0], v1 = hp[1];
        h[0]=v0.x; h[1]=v0.y; h[2]=v0.z; h[3]=v0.w;
        h[4]=v1.x; h[5]=v1.y; h[6]=v1.z; h[7]=v1.w;
    }
    const float4* nbase = (const float4*)ext + (size_t)batch * (TSTEPS * NSTATES / 4) + gm * 2;
    float4 nA0 = nbase[0], nA1 = nbase[1];
    float4 nB0 = nbase[NSTATES / 4], nB1 = nbase[NSTATES / 4 + 1];
    float* yout = y + (size_t)batch * (TSTEPS + 1) * NO;

    const int s2addr = ((lane & 3) << 3) | (lane >> 3);

    auto STEP = [&](int t, float4& nc0, float4& nc1) {
        float4 u0 = nc0, u1 = nc1;
        int tp = (t + 2 < TSTEPS) ? (t + 2) : (TSTEPS - 1);
        nc0 = nbase[(size_t)tp * (NSTATES / 4)];
        nc1 = nbase[(size_t)tp * (NSTATES / 4) + 1];

        float phi[SPT];
        #pragma unroll
        for (int k = 0; k < SPT; ++k) phi[k] = ftanh(h[k]);

        float red[12];
        #pragma unroll
        for (int r = 0; r < 8; ++r) {
            float a = phi[0] * WV[0][r];
            #pragma unroll
            for (int k = 1; k < SPT; ++k) a = __builtin_fmaf(phi[k], WV[k][r], a);
            red[r] = a;
        }
        #pragma unroll
        for (int o = 0; o < 4; ++o) {
            float a = phi[0] * WO[0][o];
            #pragma unroll
            for (int k = 1; k < SPT; ++k) a = __builtin_fmaf(phi[k], WO[k][o], a);
            red[8 + o] = a;
        }
        #pragma unroll
        for (int i = 0; i < 12; ++i) red[i] = wave_red_sum(red[i]);

        if (lane == 63) {
            *(float4*)&part[g][t & 1][gw][0] = float4{red[0], red[1], red[2], red[3]};
            *(float4*)&part[g][t & 1][gw][4] = float4{red[4], red[5], red[6], red[7]};
            *(float4*)&ybuf[g][t][gw][0]     = float4{red[8], red[9], red[10], red[11]};
        }

        // base[k] = ONEMA*h + ext (ext = alpha*(drive+noise), precomputed)
        float nn[8] = {u0.x, u0.y, u0.z, u0.w, u1.x, u1.y, u1.z, u1.w};
        float base[SPT];
        #pragma unroll
        for (int k = 0; k < SPT; ++k)
            base[k] = __builtin_fmaf(ONEMA, h[k], nn[k]);
        lds_barrier();   // shared by both groups

        float pv = (&part[g][t & 1][0][0])[s2addr];
        pv = red4(pv);
        float kf0 = readlane_f(pv, 3),  kf1 = readlane_f(pv, 11);
        float kf2 = readlane_f(pv, 19), kf3 = readlane_f(pv, 27);
        float kf4 = readlane_f(pv, 35), kf5 = readlane_f(pv, 43);
        float kf6 = readlane_f(pv, 51), kf7 = readlane_f(pv, 59);

        #pragma unroll
        for (int k = 0; k < SPT; ++k) {
            float r0 = kf0 * WU[k][0];
            r0 = __builtin_fmaf(kf1, WU[k][1], r0);
            r0 = __builtin_fmaf(kf2, WU[k][2], r0);
            r0 = __builtin_fmaf(kf3, WU[k][3], r0);
            float r1 = kf4 * WU[k][4];
            r1 = __builtin_fmaf(kf5, WU[k][5], r1);
            r1 = __builtin_fmaf(kf6, WU[k][6], r1);
            r1 = __builtin_fmaf(kf7, WU[k][7], r1);
            h[k] = base[k] + (r0 + r1);
        }
    };

    for (int t = 0; t < TSTEPS; t += 2) {
        STEP(t,     nA0, nA1);
        STEP(t + 1, nB0, nB1);
    }

    // ---- final y partials from h_T ----
    {
        float phi[SPT];
        #pragma unroll
        for (int k = 0; k < SPT; ++k) phi[k] = ftanh(h[k]);
        float yred[4];
        #pragma unroll
        for (int o = 0; o < 4; ++o) {
            float a = phi[0] * WO[0][o];
            #pragma unroll
            for (int k = 1; k < SPT; ++k) a = __builtin_fmaf(phi[k], WO[k][o], a);
            yred[o] = a;
        }
        #pragma unroll
        for (int o = 0; o < 4; ++o) yred[o] = wave_red_sum(yred[o]);
        if (lane == 63)
            *(float4*)&ybuf[g][TSTEPS][gw][0] = float4{yred[0], yred[1], yred[2], yred[3]};
    }
    lds_barrier();

    for (int idx = gm; idx < (TSTEPS + 1) * NO; idx += GTHREADS) {
        int t = idx >> 2, o = idx & 3;
        yout[idx] = (ybuf[g][t][0][o] + ybuf[g][t][1][o])
                  + (ybuf[g][t][2][o] + ybuf[g][t][3][o]);
    }
}

// =====================================================================
// Fallback (ws too small): R5/R9-style fully-fused single-batch kernel.
// =====================================================================
__global__ __launch_bounds__(256, 1)
void rnn_fallback(
    const float* __restrict__ u, const float* __restrict__ G,
    const float* __restrict__ mu, const float* __restrict__ C,
    const float* __restrict__ h0, const float* __restrict__ nl,
    const float* __restrict__ nrec, float* __restrict__ y)
{
    __shared__ float u_lds[TSTEPS * NI];
    __shared__ float c_lds[NPOP * NF * NF];
    __shared__ float mu_lds[NPOP * NF];
    __shared__ __align__(16) float part[2][4][8];
    __shared__ __align__(16) float ybuf[TSTEPS + 1][4][4];

    const int tid  = threadIdx.x;
    const int b    = blockIdx.x;
    const int lane = tid & 63;
    const int wid  = tid >> 6;
    const int p    = wid;
    const int s0   = tid * SPT;

    {
        const float4* s4 = (const float4*)(u + (size_t)b * TSTEPS * NI);
        ((float4*)u_lds)[tid]       = s4[tid];
        ((float4*)u_lds)[tid + 256] = s4[tid + 256];
    }
    {
        const float4* s4 = (const float4*)C;
        float4* dst = (float4*)c_lds;
        #pragma unroll
        for (int i = 0; i < 4; ++i) {
            int idx = tid + i * 256;
            if (idx < NPOP * NF * NF / 4) dst[idx] = s4[idx];
        }
    }
    if (tid < NPOP * NF) mu_lds[tid] = mu[tid];

    float w_p;
    {
        float g0 = G[0], g1 = G[1], g2 = G[2], g3 = G[3];
        float mx = fmaxf(fmaxf(g0, g1), fmaxf(g2, g3));
        const float L2E = 1.4426950408889634f;
        float e0 = vexp2((g0 - mx) * L2E), e1 = vexp2((g1 - mx) * L2E);
        float e2 = vexp2((g2 - mx) * L2E), e3 = vexp2((g3 - mx) * L2E);
        float inv = vrcp(e0 + e1 + e2 + e3);
        float ap = (p == 0) ? e0 : (p == 1) ? e1 : (p == 2) ? e2 : e3;
        w_p = ap * inv * (1.0f / (float)RANDN);
    }
    __syncthreads();

    float W[SPT][NF];
    #pragma unroll
    for (int f = 0; f < NF; ++f) {
        float m = mu_lds[p * NF + f];
        #pragma unroll
        for (int k = 0; k < SPT; ++k) W[k][f] = m;
    }
    #pragma unroll
    for (int pr = 0; pr < 2; ++pr) {
        float nlr[4][NF];
        #pragma unroll
        for (int kk = 0; kk < 4; ++kk) {
            const float4* s4 = (const float4*)(nl + (size_t)(s0 + pr * 4 + kk) * NF);
            #pragma unroll
            for (int q = 0; q < 7; ++q) {
                float4 v = s4[q];
                nlr[kk][q*4+0] = v.x; nlr[kk][q*4+1] = v.y;
                nlr[kk][q*4+2] = v.z; nlr[kk][q*4+3] = v.w;
            }
        }
        #pragma unroll
        for (int f = 0; f < NF; ++f) {
            const float4* cr = (const float4*)&c_lds[(p * NF + f) * NF];
            float crow[NF];
            #pragma unroll
            for (int q = 0; q < 7; ++q) {
                float4 v = cr[q];
                crow[q*4+0] = v.x; crow[q*4+1] = v.y;
                crow[q*4+2] = v.z; crow[q*4+3] = v.w;
            }
            #pragma unroll
            for (int kk = 0; kk < 4; ++kk) {
                float acc = W[pr*4+kk][f];
                #pragma unroll
                for (int ss = 0; ss < NF; ++ss)
                    acc = __builtin_fmaf(crow[ss], nlr[kk][ss], acc);
                W[pr*4+kk][f] = acc;
            }
        }
    }
    #pragma unroll
    for (int k = 0; k < SPT; ++k) {
        #pragma unroll
        for (int f = 0; f < 16; ++f) W[k][f] *= ALPHA;
        #pragma unroll
        for (int f = 16; f < NF; ++f) W[k][f] *= w_p;
    }

    float h[SPT];
    {
        const float4* hp = (const float4*)(h0 + s0);
        float4 v0 = hp[0], v1 = hp[1];
        h[0]=v0.x; h[1]=v0.y; h[2]=v0.z; h[3]=v0.w;
        h[4]=v1.x; h[5]=v1.y; h[6]=v1.z; h[7]=v1.w;
    }
    const float4* nbase = (const float4*)nrec + (size_t)b * (TSTEPS * NSTATES / 4) + tid * 2;
    float4 nA0 = nbase[0], nA1 = nbase[1];
    float4 nB0 = nbase[NSTATES / 4], nB1 = nbase[NSTATES / 4 + 1];
    float* yout = y + (size_t)b * (TSTEPS + 1) * NO;
    const int s2addr = ((lane & 3) << 3) | (lane >> 3);

    auto STEP = [&](int t, float4& nc0, float4& nc1) {
        float4 u0 = nc0, u1 = nc1;
        int tp = (t + 2 < TSTEPS) ? (t + 2) : (TSTEPS - 1);
        nc0 = nbase[(size_t)tp * (NSTATES / 4)];
        nc1 = nbase[(size_t)tp * (NSTATES / 4) + 1];

        float phi[SPT];
        #pragma unroll
        for (int k = 0; k < SPT; ++k) phi[k] = ftanh(h[k]);

        float red[12];
        #pragma unroll
        for (int r = 0; r < 8; ++r) {
            float a = phi[0] * W[0][16 + r];
            #pragma unroll
            for (int k = 1; k < SPT; ++k) a = __builtin_fmaf(phi[k], W[k][16 + r], a);
            red[r] = a;
        }
        #pragma unroll
        for (int o = 0; o < 4; ++o) {
            float a = phi[0] * W[0][24 + o];
            #pragma unroll
            for (int k = 1; k < SPT; ++k) a = __builtin_fmaf(phi[k], W[k][24 + o], a);
            red[8 + o] = a;
        }
        #pragma unroll
        for (int i = 0; i < 12; ++i) red[i] = wave_red_sum(red[i]);

        if (lane == 63) {
            *(float4*)&part[t & 1][wid][0] = float4{red[0], red[1], red[2], red[3]};
            *(float4*)&part[t & 1][wid][4] = float4{red[4], red[5], red[6], red[7]};
            *(float4*)&ybuf[t][wid][0]     = float4{red[8], red[9], red[10], red[11]};
        }

        float ut[8];
        {
            const float4* up = (const float4*)&u_lds[t * NI];
            float4 a = up[0], bb = up[1];
            ut[0]=a.x; ut[1]=a.y; ut[2]=a.z; ut[3]=a.w;
            ut[4]=bb.x; ut[5]=bb.y; ut[6]=bb.z; ut[7]=bb.w;
        }
        float nn[8] = {u0.x, u0.y, u0.z, u0.w, u1.x, u1.y, u1.z, u1.w};
        float base[SPT];
        #pragma unroll
        for (int k = 0; k < SPT; ++k) {
            float acc0 = ALPHA * nn[k];
            #pragma unroll
            for (int i = 0; i < 4; ++i) acc0 = __builtin_fmaf(ut[i], W[k][i], acc0);
            float acc1 = ut[4] * W[k][4];
            #pragma unroll
            for (int i = 5; i < 8; ++i) acc1 = __builtin_fmaf(ut[i], W[k][i], acc1);
            base[k] = __builtin_fmaf(ONEMA, h[k], acc0 + acc1);
        }
        lds_barrier();

        float pv = (&part[t & 1][0][0])[s2addr];
        pv = red4(pv);
        float kf0 = readlane_f(pv, 3),  kf1 = readlane_f(pv, 11);
        float kf2 = readlane_f(pv, 19), kf3 = readlane_f(pv, 27);
        float kf4 = readlane_f(pv, 35), kf5 = readlane_f(pv, 43);
        float kf6 = readlane_f(pv, 51), kf7 = readlane_f(pv, 59);

        #pragma unroll
        for (int k = 0; k < SPT; ++k) {
            float r0 = kf0 * W[k][8];
            r0 = __builtin_fmaf(kf1, W[k][9],  r0);
            r0 = __builtin_fmaf(kf2, W[k][10], r0);
            r0 = __builtin_fmaf(kf3, W[k][11], r0);
            float r1 = kf4 * W[k][12];
            r1 = __builtin_fmaf(kf5, W[k][13], r1);
            r1 = __builtin_fmaf(kf6, W[k][14], r1);
            r1 = __builtin_fmaf(kf7, W[k][15], r1);
            h[k] = base[k] + (r0 + r1);
        }
    };

    for (int t = 0; t < TSTEPS; t += 2) {
        STEP(t,     nA0, nA1);
        STEP(t + 1, nB0, nB1);
    }

    {
        float phi[SPT];
        #pragma unroll
        for (int k = 0; k < SPT; ++k) phi[k] = ftanh(h[k]);
        float yred[4];
        #pragma unroll
        for (int o = 0; o < 4; ++o) {
            float a = phi[0] * W[0][24 + o];
            #pragma unroll
            for (int k = 1; k < SPT; ++k) a = __builtin_fmaf(phi[k], W[k][24 + o], a);
            yred[o] = a;
        }
        #pragma unroll
        for (int o = 0; o < 4; ++o) yred[o] = wave_red_sum(yred[o]);
        if (lane == 63)
            *(float4*)&ybuf[TSTEPS][wid][0] = float4{yred[0], yred[1], yred[2], yred[3]};
    }
    lds_barrier();

    for (int idx = tid; idx < (TSTEPS + 1) * NO; idx += 256) {
        int t = idx >> 2, o = idx & 3;
        yout[idx] = (ybuf[t][0][o] + ybuf[t][1][o]) + (ybuf[t][2][o] + ybuf[t][3][o]);
    }
}

extern "C" void kernel_launch(void* const* d_in, const int* in_sizes, int n_in,
                              void* d_out, int out_size, void* d_ws, size_t ws_size,
                              hipStream_t stream) {
    const float* u    = (const float*)d_in[0];
    const float* G    = (const float*)d_in[1];
    const float* mu   = (const float*)d_in[2];
    const float* C    = (const float*)d_in[3];
    const float* h0   = (const float*)d_in[4];
    const float* nl   = (const float*)d_in[5];
    const float* nrec = (const float*)d_in[6];
    float* yp = (float*)d_out;

    const size_t need = (size_t)NBATCH * TSTEPS * NSTATES * sizeof(float); // 128 MiB
    if (ws_size >= need) {
        float* ext = (float*)d_ws;
        ext_kernel<<<dim3(NBATCH * (TSTEPS / CHUNK)), dim3(256), 0, stream>>>(
            u, mu, C, nl, nrec, ext);
        rnn_dual<<<dim3(NBATCH / GROUPS), dim3(DTHREADS), 0, stream>>>(
            G, mu, C, h0, nl, ext, yp);
    } else {
        rnn_fallback<<<dim3(NBATCH), dim3(256), 0, stream>>>(
            u, G, mu, C, h0, nl, nrec, yp);
    }
}

// Round 11
// 718.609 us; speedup vs baseline: 1.3232x; 1.3232x over previous
//
#include <hip/hip_runtime.h>

// ---- problem constants (from reference) ----
#define TSTEPS 256
#define NPOP 4
#define NI 8
#define NO 4
#define NF 28            // NI + 2*NR + NO
#define RANDN 512
#define NBATCH 64
#define NSTATES (NPOP*RANDN)   // 2048
#define ALPHA 0.2f             // DT/TAU
#define ONEMA 0.8f
#define SPT 8                  // states per thread
#define CHUNK 8                // timesteps per ext-kernel block

__device__ __forceinline__ float vexp2(float x) { return __builtin_amdgcn_exp2f(x); }
__device__ __forceinline__ float vrcp(float x)  { return __builtin_amdgcn_rcpf(x); }

// tanh(x) = 1 - 2/(e^{2x}+1)
__device__ __forceinline__ float ftanh(float x) {
    float t = vexp2(x * 2.885390081777927f);
    return __builtin_fmaf(-2.0f, vrcp(t + 1.0f), 1.0f);
}

template<int CTRL, int RM, int BM>
__device__ __forceinline__ float dpp_add(float x) {
    int v = __builtin_amdgcn_update_dpp(0, __float_as_int(x), CTRL, RM, BM, true);
    return x + __int_as_float(v);
}

// full wave64 sum -> valid in lane 63
__device__ __forceinline__ float wave_red_sum(float x) {
    x = dpp_add<0x111, 0xf, 0xf>(x);  // row_shr:1
    x = dpp_add<0x112, 0xf, 0xf>(x);  // row_shr:2
    x = dpp_add<0x114, 0xf, 0xf>(x);  // row_shr:4
    x = dpp_add<0x118, 0xf, 0xf>(x);  // row_shr:8
    x = dpp_add<0x142, 0xa, 0xf>(x);  // row_bcast:15 -> rows 1,3
    x = dpp_add<0x143, 0xc, 0xf>(x);  // row_bcast:31 -> rows 2,3
    return x;
}

// sum within each 4-lane group -> valid at lanes 4g+3
__device__ __forceinline__ float red4(float x) {
    x = dpp_add<0x111, 0xf, 0xf>(x);
    x = dpp_add<0x112, 0xf, 0xf>(x);
    return x;
}

// barrier with LDS-only ordering (vmcnt stays in flight across it)
__device__ __forceinline__ void lds_barrier() {
    asm volatile("s_waitcnt lgkmcnt(0)\n\ts_barrier" ::: "memory");
}

__device__ __forceinline__ float readlane_f(float x, int l) {
    return __uint_as_float(__builtin_amdgcn_readlane(__float_as_uint(x), l));
}

// =====================================================================
// Pre-kernel: ext[b][t][s] = ALPHA*( noise_rec[b][t][s] + I[s,:]·u[b][t,:] )
// 2048 blocks. All 16 noise loads issued before compute (latency hiding).
// =====================================================================
__global__ __launch_bounds__(256, 2) void ext_kernel(
    const float* __restrict__ u,      // [B][T][NI]
    const float* __restrict__ mu,     // [NPOP][NF]
    const float* __restrict__ C,      // [NPOP][NF][NF]
    const float* __restrict__ nl,     // [NPOP][RANDN][NF]
    const float* __restrict__ nrec,   // [B][T][NSTATES]
    float* __restrict__ ext)          // [B][T][NSTATES]
{
    __shared__ float c_lds[NPOP * NF * NF];
    __shared__ float u_sh[CHUNK * NI];

    const int tid = threadIdx.x;
    const int b   = blockIdx.x >> 5;                 // 32 chunks per batch
    const int tch = (blockIdx.x & 31) * CHUNK;
    const int p   = tid >> 6;
    const int s0  = tid * SPT;

    {
        const float4* src = (const float4*)C;
        float4* dst = (float4*)c_lds;
        #pragma unroll
        for (int i = 0; i < 4; ++i) {
            int idx = tid + i * 256;
            if (idx < NPOP * NF * NF / 4) dst[idx] = src[idx];
        }
    }
    if (tid < CHUNK * NI / 4)
        ((float4*)u_sh)[tid] = ((const float4*)(u + (size_t)b * TSTEPS * NI + tch * NI))[tid];

    // issue ALL noise loads up front (16 float4 in flight)
    const size_t rowq = NSTATES / 4;
    const float4* nb = (const float4*)nrec + ((size_t)b * TSTEPS + tch) * rowq + tid * 2;
    float4 m[CHUNK][2];
    #pragma unroll
    for (int j = 0; j < CHUNK; ++j) {
        m[j][0] = nb[(size_t)j * rowq];
        m[j][1] = nb[(size_t)j * rowq + 1];
    }
    __syncthreads();

    // WI[k][i] = I-loading column i for state s0+k
    float WI[SPT][8];
    #pragma unroll
    for (int c = 0; c < 8; ++c) {
        float mm = mu[p * NF + c];
        #pragma unroll
        for (int k = 0; k < SPT; ++k) WI[k][c] = mm;
    }
    #pragma unroll
    for (int pr = 0; pr < 4; ++pr) {
        float nlr[2][NF];
        #pragma unroll
        for (int kk = 0; kk < 2; ++kk) {
            const float4* src = (const float4*)(nl + (size_t)(s0 + pr * 2 + kk) * NF);
            #pragma unroll
            for (int q = 0; q < 7; ++q) {
                float4 v = src[q];
                nlr[kk][q*4+0] = v.x; nlr[kk][q*4+1] = v.y;
                nlr[kk][q*4+2] = v.z; nlr[kk][q*4+3] = v.w;
            }
        }
        #pragma unroll
        for (int f = 0; f < 8; ++f) {
            const float4* cr = (const float4*)&c_lds[(p * NF + f) * NF];
            float crow[NF];
            #pragma unroll
            for (int q = 0; q < 7; ++q) {
                float4 v = cr[q];
                crow[q*4+0] = v.x; crow[q*4+1] = v.y;
                crow[q*4+2] = v.z; crow[q*4+3] = v.w;
            }
            #pragma unroll
            for (int kk = 0; kk < 2; ++kk) {
                float acc = WI[pr*2+kk][f];
                #pragma unroll
                for (int ss = 0; ss < NF; ++ss)
                    acc = __builtin_fmaf(crow[ss], nlr[kk][ss], acc);
                WI[pr*2+kk][f] = acc;
            }
        }
    }

    float4* eb = (float4*)ext + ((size_t)b * TSTEPS + tch) * rowq + tid * 2;
    #pragma unroll
    for (int j = 0; j < CHUNK; ++j) {
        float ut[8];
        #pragma unroll
        for (int i = 0; i < 8; ++i) ut[i] = u_sh[j * NI + i];
        float nn[8] = {m[j][0].x, m[j][0].y, m[j][0].z, m[j][0].w,
                       m[j][1].x, m[j][1].y, m[j][1].z, m[j][1].w};
        float ex[8];
        #pragma unroll
        for (int k = 0; k < SPT; ++k) {
            float a = nn[k];
            #pragma unroll
            for (int i = 0; i < 8; ++i) a = __builtin_fmaf(ut[i], WI[k][i], a);
            ex[k] = a * ALPHA;
        }
        eb[(size_t)j * rowq]     = float4{ex[0], ex[1], ex[2], ex[3]};
        eb[(size_t)j * rowq + 1] = float4{ex[4], ex[5], ex[6], ex[7]};
    }
}

// =====================================================================
// Dual-batch sequential kernel: each THREAD runs two batches over the
// same 8 states, sharing W. 256 threads / 4 waves / 1 wave per SIMD ->
// 256-VGPR budget (the only clean-allocation regime observed).
// One shared barrier retires two batch-steps.
// =====================================================================
__global__ __launch_bounds__(256, 1)
void rnn_dual2(
    const float* __restrict__ G,      // [NPOP]
    const float* __restrict__ mu,     // [NPOP][NF]
    const float* __restrict__ C,      // [NPOP][NF][NF]
    const float* __restrict__ h0,     // [NPOP][RANDN]
    const float* __restrict__ nl,     // [NPOP][RANDN][NF]
    const float* __restrict__ ext,    // [B][T][NSTATES]  (precomputed)
    float* __restrict__ y)            // [B][T+1][NO]
{
    __shared__ float c_lds[NPOP * NF * NF];
    __shared__ float mu_lds[NPOP * NF];
    __shared__ __align__(16) float part[2][2][4][8];          // [batch][dbuf][wave][8]
    __shared__ __align__(16) float ybuf[2][TSTEPS + 1][4][4]; // [batch][t][wave][4]

    const int tid  = threadIdx.x;
    const int lane = tid & 63;
    const int wid  = tid >> 6;
    const int p    = wid;               // wave = population
    const int s0   = tid * SPT;
    const int bA   = blockIdx.x * 2;
    const int bB   = bA + 1;

    {
        const float4* s4 = (const float4*)C;
        float4* dst = (float4*)c_lds;
        #pragma unroll
        for (int i = 0; i < 4; ++i) {
            int idx = tid + i * 256;
            if (idx < NPOP * NF * NF / 4) dst[idx] = s4[idx];
        }
    }
    if (tid < NPOP * NF) mu_lds[tid] = mu[tid];

    float w_p;
    {
        float g0 = G[0], g1 = G[1], g2 = G[2], g3 = G[3];
        float mx = fmaxf(fmaxf(g0, g1), fmaxf(g2, g3));
        const float L2E = 1.4426950408889634f;
        float e0 = vexp2((g0 - mx) * L2E), e1 = vexp2((g1 - mx) * L2E);
        float e2 = vexp2((g2 - mx) * L2E), e3 = vexp2((g3 - mx) * L2E);
        float inv = vrcp(e0 + e1 + e2 + e3);
        float ap = (p == 0) ? e0 : (p == 1) ? e1 : (p == 2) ? e2 : e3;
        w_p = ap * inv * (1.0f / (float)RANDN);
    }
    __syncthreads();

    // ---- loading rows (shared across both batches) ----
    float WU[SPT][8];          // alpha*U (f=8..15)
    float WV[SPT][8];          // w*V     (f=16..23)
    float WO[SPT][4];          // w*O     (f=24..27)

    #pragma unroll
    for (int pr = 0; pr < 4; ++pr) {       // 2 states at a time
        float nlr[2][NF];
        #pragma unroll
        for (int kk = 0; kk < 2; ++kk) {
            const float4* s4 = (const float4*)(nl + (size_t)(s0 + pr * 2 + kk) * NF);
            #pragma unroll
            for (int q = 0; q < 7; ++q) {
                float4 v = s4[q];
                nlr[kk][q*4+0] = v.x; nlr[kk][q*4+1] = v.y;
                nlr[kk][q*4+2] = v.z; nlr[kk][q*4+3] = v.w;
            }
        }
        #pragma unroll
        for (int f = 8; f < NF; ++f) {
            const float4* cr = (const float4*)&c_lds[(p * NF + f) * NF];
            float crow[NF];
            #pragma unroll
            for (int q = 0; q < 7; ++q) {
                float4 v = cr[q];
                crow[q*4+0] = v.x; crow[q*4+1] = v.y;
                crow[q*4+2] = v.z; crow[q*4+3] = v.w;
            }
            #pragma unroll
            for (int kk = 0; kk < 2; ++kk) {
                int k = pr * 2 + kk;
                float acc = mu_lds[p * NF + f];
                #pragma unroll
                for (int ss = 0; ss < NF; ++ss)
                    acc = __builtin_fmaf(crow[ss], nlr[kk][ss], acc);
                if (f < 16)      WU[k][f - 8]  = acc;
                else if (f < 24) WV[k][f - 16] = acc;
                else             WO[k][f - 24] = acc;
            }
        }
    }
    #pragma unroll
    for (int k = 0; k < SPT; ++k) {
        #pragma unroll
        for (int c = 0; c < 8; ++c) { WU[k][c] *= ALPHA; WV[k][c] *= w_p; }
        #pragma unroll
        for (int c = 0; c < 4; ++c) WO[k][c] *= w_p;
    }

    // ---- h init (same h0 for both batches) ----
    float hA[SPT], hB[SPT];
    {
        const float4* hp = (const float4*)(h0 + s0);
        float4 v0 = hp[0], v1 = hp[1];
        hA[0]=v0.x; hA[1]=v0.y; hA[2]=v0.z; hA[3]=v0.w;
        hA[4]=v1.x; hA[5]=v1.y; hA[6]=v1.z; hA[7]=v1.w;
        #pragma unroll
        for (int k = 0; k < SPT; ++k) hB[k] = hA[k];
    }
    const size_t rowq = NSTATES / 4;
    const float4* nbA = (const float4*)ext + (size_t)bA * (TSTEPS * NSTATES / 4) + tid * 2;
    const float4* nbB = (const float4*)ext + (size_t)bB * (TSTEPS * NSTATES / 4) + tid * 2;
    float4 eA0[2] = {nbA[0], nbA[1]};            // step t   (A)
    float4 eA1[2] = {nbA[rowq], nbA[rowq + 1]};  // step t+1 (A)
    float4 eB0[2] = {nbB[0], nbB[1]};
    float4 eB1[2] = {nbB[rowq], nbB[rowq + 1]};

    const int s2addr = ((lane & 3) << 3) | (lane >> 3);

    // one reduction+publish phase for a batch (pre-barrier part)
    auto RPHASE = [&](float h[SPT], const float4 ec[2], float base[SPT],
                      float* partw, float* ybw) {
        float phi[SPT];
        #pragma unroll
        for (int k = 0; k < SPT; ++k) phi[k] = ftanh(h[k]);
        float red[12];
        #pragma unroll
        for (int r = 0; r < 8; ++r) {
            float a = phi[0] * WV[0][r];
            #pragma unroll
            for (int k = 1; k < SPT; ++k) a = __builtin_fmaf(phi[k], WV[k][r], a);
            red[r] = a;
        }
        #pragma unroll
        for (int o = 0; o < 4; ++o) {
            float a = phi[0] * WO[0][o];
            #pragma unroll
            for (int k = 1; k < SPT; ++k) a = __builtin_fmaf(phi[k], WO[k][o], a);
            red[8 + o] = a;
        }
        #pragma unroll
        for (int i = 0; i < 12; ++i) red[i] = wave_red_sum(red[i]);
        if (lane == 63) {
            *(float4*)(partw + 0) = float4{red[0], red[1], red[2], red[3]};
            *(float4*)(partw + 4) = float4{red[4], red[5], red[6], red[7]};
            *(float4*)ybw         = float4{red[8], red[9], red[10], red[11]};
        }
        float nn[8] = {ec[0].x, ec[0].y, ec[0].z, ec[0].w,
                       ec[1].x, ec[1].y, ec[1].z, ec[1].w};
        #pragma unroll
        for (int k = 0; k < SPT; ++k)
            base[k] = __builtin_fmaf(ONEMA, h[k], nn[k]);
    };

    // stage-2 + h update for a batch (post-barrier part)
    auto UPHASE = [&](float h[SPT], const float base[SPT], const float* partflat) {
        float pv = partflat[s2addr];
        pv = red4(pv);
        float kf0 = readlane_f(pv, 3),  kf1 = readlane_f(pv, 11);
        float kf2 = readlane_f(pv, 19), kf3 = readlane_f(pv, 27);
        float kf4 = readlane_f(pv, 35), kf5 = readlane_f(pv, 43);
        float kf6 = readlane_f(pv, 51), kf7 = readlane_f(pv, 59);
        #pragma unroll
        for (int k = 0; k < SPT; ++k) {
            float r0 = kf0 * WU[k][0];
            r0 = __builtin_fmaf(kf1, WU[k][1], r0);
            r0 = __builtin_fmaf(kf2, WU[k][2], r0);
            r0 = __builtin_fmaf(kf3, WU[k][3], r0);
            float r1 = kf4 * WU[k][4];
            r1 = __builtin_fmaf(kf5, WU[k][5], r1);
            r1 = __builtin_fmaf(kf6, WU[k][6], r1);
            r1 = __builtin_fmaf(kf7, WU[k][7], r1);
            h[k] = base[k] + (r0 + r1);
        }
    };

    auto STEP = [&](int t, float4 ecA[2], float4 ecB[2]) {
        // consume ecA/ecB; refill with step t+2 (stays in flight across barrier)
        float4 uA[2] = {ecA[0], ecA[1]};
        float4 uB[2] = {ecB[0], ecB[1]};
        size_t tp = (size_t)((t + 2 < TSTEPS) ? (t + 2) : (TSTEPS - 1)) * rowq;
        ecA[0] = nbA[tp]; ecA[1] = nbA[tp + 1];
        ecB[0] = nbB[tp]; ecB[1] = nbB[tp + 1];

        float baseA[SPT], baseB[SPT];
        RPHASE(hA, uA, baseA, &part[0][t & 1][wid][0], &ybuf[0][t][wid][0]);
        RPHASE(hB, uB, baseB, &part[1][t & 1][wid][0], &ybuf[1][t][wid][0]);
        lds_barrier();
        UPHASE(hA, baseA, &part[0][t & 1][0][0]);
        UPHASE(hB, baseB, &part[1][t & 1][0][0]);
    };

    for (int t = 0; t < TSTEPS; t += 2) {
        STEP(t,     eA0, eB0);
        STEP(t + 1, eA1, eB1);
    }

    // ---- final y partials from h_T (both batches) ----
    #pragma unroll
    for (int gb = 0; gb < 2; ++gb) {
        float* h = gb ? hB : hA;
        float phi[SPT];
        #pragma unroll
        for (int k = 0; k < SPT; ++k) phi[k] = ftanh(h[k]);
        float yred[4];
        #pragma unroll
        for (int o = 0; o < 4; ++o) {
            float a = phi[0] * WO[0][o];
            #pragma unroll
            for (int k = 1; k < SPT; ++k) a = __builtin_fmaf(phi[k], WO[k][o], a);
            yred[o] = a;
        }
        #pragma unroll
        for (int o = 0; o < 4; ++o) yred[o] = wave_red_sum(yred[o]);
        if (lane == 63)
            *(float4*)&ybuf[gb][TSTEPS][wid][0] = float4{yred[0], yred[1], yred[2], yred[3]};
    }
    lds_barrier();

    // ---- final y writeout: 2 batches x 1028 outputs ----
    float* youtA = y + (size_t)bA * (TSTEPS + 1) * NO;
    float* youtB = y + (size_t)bB * (TSTEPS + 1) * NO;
    for (int idx = tid; idx < (TSTEPS + 1) * NO; idx += 256) {
        int t = idx >> 2, o = idx & 3;
        youtA[idx] = (ybuf[0][t][0][o] + ybuf[0][t][1][o])
                   + (ybuf[0][t][2][o] + ybuf[0][t][3][o]);
        youtB[idx] = (ybuf[1][t][0][o] + ybuf[1][t][1][o])
                   + (ybuf[1][t][2][o] + ybuf[1][t][3][o]);
    }
}

// =====================================================================
// Fallback (ws too small): R9-style fully-fused single-batch kernel.
// =====================================================================
__global__ __launch_bounds__(256, 1)
void rnn_fallback(
    const float* __restrict__ u, const float* __restrict__ G,
    const float* __restrict__ mu, const float* __restrict__ C,
    const float* __restrict__ h0, const float* __restrict__ nl,
    const float* __restrict__ nrec, float* __restrict__ y)
{
    __shared__ float u_lds[TSTEPS * NI];
    __shared__ float c_lds[NPOP * NF * NF];
    __shared__ float mu_lds[NPOP * NF];
    __shared__ __align__(16) float part[2][4][8];
    __shared__ __align__(16) float ybuf[TSTEPS + 1][4][4];

    const int tid  = threadIdx.x;
    const int b    = blockIdx.x;
    const int lane = tid & 63;
    const int wid  = tid >> 6;
    const int p    = wid;
    const int s0   = tid * SPT;

    {
        const float4* s4 = (const float4*)(u + (size_t)b * TSTEPS * NI);
        ((float4*)u_lds)[tid]       = s4[tid];
        ((float4*)u_lds)[tid + 256] = s4[tid + 256];
    }
    {
        const float4* s4 = (const float4*)C;
        float4* dst = (float4*)c_lds;
        #pragma unroll
        for (int i = 0; i < 4; ++i) {
            int idx = tid + i * 256;
            if (idx < NPOP * NF * NF / 4) dst[idx] = s4[idx];
        }
    }
    if (tid < NPOP * NF) mu_lds[tid] = mu[tid];

    float w_p;
    {
        float g0 = G[0], g1 = G[1], g2 = G[2], g3 = G[3];
        float mx = fmaxf(fmaxf(g0, g1), fmaxf(g2, g3));
        const float L2E = 1.4426950408889634f;
        float e0 = vexp2((g0 - mx) * L2E), e1 = vexp2((g1 - mx) * L2E);
        float e2 = vexp2((g2 - mx) * L2E), e3 = vexp2((g3 - mx) * L2E);
        float inv = vrcp(e0 + e1 + e2 + e3);
        float ap = (p == 0) ? e0 : (p == 1) ? e1 : (p == 2) ? e2 : e3;
        w_p = ap * inv * (1.0f / (float)RANDN);
    }
    __syncthreads();

    float W[SPT][NF];
    #pragma unroll
    for (int f = 0; f < NF; ++f) {
        float m = mu_lds[p * NF + f];
        #pragma unroll
        for (int k = 0; k < SPT; ++k) W[k][f] = m;
    }
    #pragma unroll
    for (int pr = 0; pr < 2; ++pr) {
        float nlr[4][NF];
        #pragma unroll
        for (int kk = 0; kk < 4; ++kk) {
            const float4* s4 = (const float4*)(nl + (size_t)(s0 + pr * 4 + kk) * NF);
            #pragma unroll
            for (int q = 0; q < 7; ++q) {
                float4 v = s4[q];
                nlr[kk][q*4+0] = v.x; nlr[kk][q*4+1] = v.y;
                nlr[kk][q*4+2] = v.z; nlr[kk][q*4+3] = v.w;
            }
        }
        #pragma unroll
        for (int f = 0; f < NF; ++f) {
            const float4* cr = (const float4*)&c_lds[(p * NF + f) * NF];
            float crow[NF];
            #pragma unroll
            for (int q = 0; q < 7; ++q) {
                float4 v = cr[q];
                crow[q*4+0] = v.x; crow[q*4+1] = v.y;
                crow[q*4+2] = v.z; crow[q*4+3] = v.w;
            }
            #pragma unroll
            for (int kk = 0; kk < 4; ++kk) {
                float acc = W[pr*4+kk][f];
                #pragma unroll
                for (int ss = 0; ss < NF; ++ss)
                    acc = __builtin_fmaf(crow[ss], nlr[kk][ss], acc);
                W[pr*4+kk][f] = acc;
            }
        }
    }
    #pragma unroll
    for (int k = 0; k < SPT; ++k) {
        #pragma unroll
        for (int f = 0; f < 16; ++f) W[k][f] *= ALPHA;
        #pragma unroll
        for (int f = 16; f < NF; ++f) W[k][f] *= w_p;
    }

    float h[SPT];
    {
        const float4* hp = (const float4*)(h0 + s0);
        float4 v0 = hp[0], v1 = hp[1];
        h[0]=v0.x; h[1]=v0.y; h[2]=v0.z; h[3]=v0.w;
        h[4]=v1.x; h[5]=v1.y; h[6]=v1.z; h[7]=v1.w;
    }
    const float4* nbase = (const float4*)nrec + (size_t)b * (TSTEPS * NSTATES / 4) + tid * 2;
    float4 nA0 = nbase[0], nA1 = nbase[1];
    float4 nB0 = nbase[NSTATES / 4], nB1 = nbase[NSTATES / 4 + 1];
    float* yout = y + (size_t)b * (TSTEPS + 1) * NO;
    const int s2addr = ((lane & 3) << 3) | (lane >> 3);

    auto STEP = [&](int t, float4& nc0, float4& nc1) {
        float4 u0 = nc0, u1 = nc1;
        int tp = (t + 2 < TSTEPS) ? (t + 2) : (TSTEPS - 1);
        nc0 = nbase[(size_t)tp * (NSTATES / 4)];
        nc1 = nbase[(size_t)tp * (NSTATES / 4) + 1];

        float phi[SPT];
        #pragma unroll
        for (int k = 0; k < SPT; ++k) phi[k] = ftanh(h[k]);

        float red[12];
        #pragma unroll
        for (int r = 0; r < 8; ++r) {
            float a = phi[0] * W[0][16 + r];
            #pragma unroll
            for (int k = 1; k < SPT; ++k) a = __builtin_fmaf(phi[k], W[k][16 + r], a);
            red[r] = a;
        }
        #pragma unroll
        for (int o = 0; o < 4; ++o) {
            float a = phi[0] * W[0][24 + o];
            #pragma unroll
            for (int k = 1; k < SPT; ++k) a = __builtin_fmaf(phi[k], W[k][24 + o], a);
            red[8 + o] = a;
        }
        #pragma unroll
        for (int i = 0; i < 12; ++i) red[i] = wave_red_sum(red[i]);

        if (lane == 63) {
            *(float4*)&part[t & 1][wid][0] = float4{red[0], red[1], red[2], red[3]};
            *(float4*)&part[t & 1][wid][4] = float4{red[4], red[5], red[6], red[7]};
            *(float4*)&ybuf[t][wid][0]     = float4{red[8], red[9], red[10], red[11]};
        }

        float ut[8];
        {
            const float4* up = (const float4*)&u_lds[t * NI];
            float4 a = up[0], bb = up[1];
            ut[0]=a.x; ut[1]=a.y; ut[2]=a.z; ut[3]=a.w;
            ut[4]=bb.x; ut[5]=bb.y; ut[6]=bb.z; ut[7]=bb.w;
        }
        float nn[8] = {u0.x, u0.y, u0.z, u0.w, u1.x, u1.y, u1.z, u1.w};
        float base[SPT];
        #pragma unroll
        for (int k = 0; k < SPT; ++k) {
            float acc0 = ALPHA * nn[k];
            #pragma unroll
            for (int i = 0; i < 4; ++i) acc0 = __builtin_fmaf(ut[i], W[k][i], acc0);
            float acc1 = ut[4] * W[k][4];
            #pragma unroll
            for (int i = 5; i < 8; ++i) acc1 = __builtin_fmaf(ut[i], W[k][i], acc1);
            base[k] = __builtin_fmaf(ONEMA, h[k], acc0 + acc1);
        }
        lds_barrier();

        float pv = (&part[t & 1][0][0])[s2addr];
        pv = red4(pv);
        float kf0 = readlane_f(pv, 3),  kf1 = readlane_f(pv, 11);
        float kf2 = readlane_f(pv, 19), kf3 = readlane_f(pv, 27);
        float kf4 = readlane_f(pv, 35), kf5 = readlane_f(pv, 43);
        float kf6 = readlane_f(pv, 51), kf7 = readlane_f(pv, 59);

        #pragma unroll
        for (int k = 0; k < SPT; ++k) {
            float r0 = kf0 * W[k][8];
            r0 = __builtin_fmaf(kf1, W[k][9],  r0);
            r0 = __builtin_fmaf(kf2, W[k][10], r0);
            r0 = __builtin_fmaf(kf3, W[k][11], r0);
            float r1 = kf4 * W[k][12];
            r1 = __builtin_fmaf(kf5, W[k][13], r1);
            r1 = __builtin_fmaf(kf6, W[k][14], r1);
            r1 = __builtin_fmaf(kf7, W[k][15], r1);
            h[k] = base[k] + (r0 + r1);
        }
    };

    for (int t = 0; t < TSTEPS; t += 2) {
        STEP(t,     nA0, nA1);
        STEP(t + 1, nB0, nB1);
    }

    {
        float phi[SPT];
        #pragma unroll
        for (int k = 0; k < SPT; ++k) phi[k] = ftanh(h[k]);
        float yred[4];
        #pragma unroll
        for (int o = 0; o < 4; ++o) {
            float a = phi[0] * W[0][24 + o];
            #pragma unroll
            for (int k = 1; k < SPT; ++k) a = __builtin_fmaf(phi[k], W[k][24 + o], a);
            yred[o] = a;
        }
        #pragma unroll
        for (int o = 0; o < 4; ++o) yred[o] = wave_red_sum(yred[o]);
        if (lane == 63)
            *(float4*)&ybuf[TSTEPS][wid][0] = float4{yred[0], yred[1], yred[2], yred[3]};
    }
    lds_barrier();

    for (int idx = tid; idx < (TSTEPS + 1) * NO; idx += 256) {
        int t = idx >> 2, o = idx & 3;
        yout[idx] = (ybuf[t][0][o] + ybuf[t][1][o]) + (ybuf[t][2][o] + ybuf[t][3][o]);
    }
}

extern "C" void kernel_launch(void* const* d_in, const int* in_sizes, int n_in,
                              void* d_out, int out_size, void* d_ws, size_t ws_size,
                              hipStream_t stream) {
    const float* u    = (const float*)d_in[0];
    const float* G    = (const float*)d_in[1];
    const float* mu   = (const float*)d_in[2];
    const float* C    = (const float*)d_in[3];
    const float* h0   = (const float*)d_in[4];
    const float* nl   = (const float*)d_in[5];
    const float* nrec = (const float*)d_in[6];
    float* yp = (float*)d_out;

    const size_t need = (size_t)NBATCH * TSTEPS * NSTATES * sizeof(float); // 128 MiB
    if (ws_size >= need) {
        float* ext = (float*)d_ws;
        ext_kernel<<<dim3(NBATCH * (TSTEPS / CHUNK)), dim3(256), 0, stream>>>(
            u, mu, C, nl, nrec, ext);
        rnn_dual2<<<dim3(NBATCH / 2), dim3(256), 0, stream>>>(
            G, mu, C, h0, nl, ext, yp);
    } else {
        rnn_fallback<<<dim3(NBATCH), dim3(256), 0, stream>>>(
            u, G, mu, C, h0, nl, nrec, yp);
    }
}

// Round 13
// 383.257 us; speedup vs baseline: 2.4810x; 1.8750x over previous
//
#include <hip/hip_runtime.h>

// ---- problem constants (from reference) ----
#define TSTEPS 256
#define NPOP 4
#define NI 8
#define NO 4
#define NF 28            // NI + 2*NR + NO
#define RANDN 512
#define NBATCH 64
#define NSTATES (NPOP*RANDN)   // 2048
#define THREADS 256            // 4 waves; wave w = population w
#define SPT 8                  // states per thread
#define ALPHA 0.2f             // DT/TAU
#define ONEMA 0.8f
#define CHUNK 16               // timesteps per ext-kernel block (R9-exact)

typedef float v2f __attribute__((ext_vector_type(2)));

__device__ __forceinline__ v2f fma2(v2f a, v2f b, v2f c) {
    return __builtin_elementwise_fma(a, b, c);
}
__device__ __forceinline__ v2f s2(float x) { return (v2f){x, x}; }
__device__ __forceinline__ v2f mk2(float x, float y) { return (v2f){x, y}; }

__device__ __forceinline__ float vexp2(float x) { return __builtin_amdgcn_exp2f(x); }
__device__ __forceinline__ float vrcp(float x)  { return __builtin_amdgcn_rcpf(x); }

// packed tanh: 1 - 2/(e^{2x}+1); exp/rcp scalar (no packed transcendental)
__device__ __forceinline__ v2f ftanh2(v2f x) {
    v2f m = x * 2.885390081777927f;
    v2f e = mk2(vexp2(m.x), vexp2(m.y));
    v2f d = e + 1.0f;
    v2f r = mk2(vrcp(d.x), vrcp(d.y));
    return fma2(s2(-2.0f), r, s2(1.0f));
}

__device__ __forceinline__ float ftanh(float x) {
    float t = vexp2(x * 2.885390081777927f);
    return __builtin_fmaf(-2.0f, vrcp(t + 1.0f), 1.0f);
}

template<int CTRL, int RM, int BM>
__device__ __forceinline__ float dpp_add(float x) {
    int v = __builtin_amdgcn_update_dpp(0, __float_as_int(x), CTRL, RM, BM, true);
    return x + __int_as_float(v);
}

// full wave64 sum -> valid in lane 63
__device__ __forceinline__ float wave_red_sum(float x) {
    x = dpp_add<0x111, 0xf, 0xf>(x);  // row_shr:1
    x = dpp_add<0x112, 0xf, 0xf>(x);  // row_shr:2
    x = dpp_add<0x114, 0xf, 0xf>(x);  // row_shr:4
    x = dpp_add<0x118, 0xf, 0xf>(x);  // row_shr:8
    x = dpp_add<0x142, 0xa, 0xf>(x);  // row_bcast:15 -> rows 1,3
    x = dpp_add<0x143, 0xc, 0xf>(x);  // row_bcast:31 -> rows 2,3
    return x;
}

// sum within each 4-lane group -> valid at lanes 4g+3
__device__ __forceinline__ float red4(float x) {
    x = dpp_add<0x111, 0xf, 0xf>(x);
    x = dpp_add<0x112, 0xf, 0xf>(x);
    return x;
}

// barrier with LDS-only ordering (vmcnt stays in flight across it)
__device__ __forceinline__ void lds_barrier() {
    asm volatile("s_waitcnt lgkmcnt(0)\n\ts_barrier" ::: "memory");
}

__device__ __forceinline__ float readlane_f(float x, int l) {
    return __uint_as_float(__builtin_amdgcn_readlane(__float_as_uint(x), l));
}

// =====================================================================
// Pre-kernel (R9-exact): ext = ALPHA*(noise + I·u). 1024 blocks, BW-bound.
// =====================================================================
__global__ __launch_bounds__(256, 2) void ext_kernel(
    const float* __restrict__ u,
    const float* __restrict__ mu,
    const float* __restrict__ C,
    const float* __restrict__ nl,
    const float* __restrict__ nrec,
    float* __restrict__ ext)
{
    __shared__ float c_lds[NPOP * NF * NF];
    __shared__ float u_sh[CHUNK * NI];

    const int tid = threadIdx.x;
    const int b   = blockIdx.x >> 4;
    const int tch = (blockIdx.x & 15) * CHUNK;
    const int p   = tid >> 6;
    const int s0  = tid * SPT;

    {
        const float4* src = (const float4*)C;
        float4* dst = (float4*)c_lds;
        #pragma unroll
        for (int i = 0; i < 4; ++i) {
            int idx = tid + i * 256;
            if (idx < NPOP * NF * NF / 4) dst[idx] = src[idx];
        }
    }
    if (tid < CHUNK * NI / 4)
        ((float4*)u_sh)[tid] = ((const float4*)(u + (size_t)b * TSTEPS * NI + tch * NI))[tid];
    __syncthreads();

    float WI[SPT][8];
    #pragma unroll
    for (int c = 0; c < 8; ++c) {
        float m = mu[p * NF + c];
        #pragma unroll
        for (int k = 0; k < SPT; ++k) WI[k][c] = m;
    }
    #pragma unroll
    for (int pr = 0; pr < 4; ++pr) {
        float nlr[2][NF];
        #pragma unroll
        for (int kk = 0; kk < 2; ++kk) {
            const float4* src = (const float4*)(nl + (size_t)(s0 + pr * 2 + kk) * NF);
            #pragma unroll
            for (int q = 0; q < 7; ++q) {
                float4 v = src[q];
                nlr[kk][q*4+0] = v.x; nlr[kk][q*4+1] = v.y;
                nlr[kk][q*4+2] = v.z; nlr[kk][q*4+3] = v.w;
            }
        }
        #pragma unroll
        for (int f = 0; f < 8; ++f) {
            const float4* cr = (const float4*)&c_lds[(p * NF + f) * NF];
            float crow[NF];
            #pragma unroll
            for (int q = 0; q < 7; ++q) {
                float4 v = cr[q];
                crow[q*4+0] = v.x; crow[q*4+1] = v.y;
                crow[q*4+2] = v.z; crow[q*4+3] = v.w;
            }
            #pragma unroll
            for (int kk = 0; kk < 2; ++kk) {
                float acc = WI[pr*2+kk][f];
                #pragma unroll
                for (int ss = 0; ss < NF; ++ss)
                    acc = __builtin_fmaf(crow[ss], nlr[kk][ss], acc);
                WI[pr*2+kk][f] = acc;
            }
        }
    }
    #pragma unroll
    for (int k = 0; k < SPT; ++k)
        #pragma unroll
        for (int c = 0; c < 8; ++c) WI[k][c] *= ALPHA;

    const size_t rowq = NSTATES / 4;
    const float4* nb = (const float4*)nrec + ((size_t)b * TSTEPS + tch) * rowq + tid * 2;
    float4*       eb = (float4*)ext        + ((size_t)b * TSTEPS + tch) * rowq + tid * 2;

    #pragma unroll 2
    for (int j = 0; j < CHUNK; ++j) {
        float4 m0 = nb[(size_t)j * rowq];
        float4 m1 = nb[(size_t)j * rowq + 1];
        float ut[8];
        #pragma unroll
        for (int i = 0; i < 8; ++i) ut[i] = u_sh[j * NI + i];
        float nn[8] = {m0.x, m0.y, m0.z, m0.w, m1.x, m1.y, m1.z, m1.w};
        float ex[8];
        #pragma unroll
        for (int k = 0; k < SPT; ++k) {
            float a = ALPHA * nn[k];
            #pragma unroll
            for (int i = 0; i < 8; ++i) a = __builtin_fmaf(ut[i], WI[k][i], a);
            ex[k] = a;
        }
        eb[(size_t)j * rowq]     = float4{ex[0], ex[1], ex[2], ex[3]};
        eb[(size_t)j * rowq + 1] = float4{ex[4], ex[5], ex[6], ex[7]};
    }
}

// =====================================================================
// Sequential kernel (R9 structure + packed fp32 math + scalar prefetch ptr)
// =====================================================================
__global__ __launch_bounds__(THREADS, 1)
void rnn_fused(
    const float* __restrict__ G,
    const float* __restrict__ mu,
    const float* __restrict__ C,
    const float* __restrict__ h0,
    const float* __restrict__ nl,
    const float* __restrict__ ext,    // [B][T][NSTATES] precomputed
    float* __restrict__ y)
{
    __shared__ float c_lds[NPOP * NF * NF];
    __shared__ float mu_lds[NPOP * NF];
    __shared__ __align__(16) float part[2][4][8];
    __shared__ __align__(16) float ybuf[TSTEPS + 1][4][4];

    const int tid  = threadIdx.x;
    const int b    = blockIdx.x;
    const int lane = tid & 63;
    const int wid  = tid >> 6;
    const int p    = wid;               // wave = population
    const int s0   = tid * SPT;

    {
        const float4* s4 = (const float4*)C;
        float4* dst = (float4*)c_lds;
        #pragma unroll
        for (int i = 0; i < 4; ++i) {
            int idx = tid + i * THREADS;
            if (idx < NPOP * NF * NF / 4) dst[idx] = s4[idx];
        }
    }
    if (tid < NPOP * NF) mu_lds[tid] = mu[tid];

    float w_p;
    {
        float g0 = G[0], g1 = G[1], g2 = G[2], g3 = G[3];
        float mx = fmaxf(fmaxf(g0, g1), fmaxf(g2, g3));
        const float L2E = 1.4426950408889634f;
        float e0 = vexp2((g0 - mx) * L2E), e1 = vexp2((g1 - mx) * L2E);
        float e2 = vexp2((g2 - mx) * L2E), e3 = vexp2((g3 - mx) * L2E);
        float inv = vrcp(e0 + e1 + e2 + e3);
        float ap = (p == 0) ? e0 : (p == 1) ? e1 : (p == 2) ? e2 : e3;
        w_p = ap * inv * (1.0f / (float)RANDN);
    }
    __syncthreads();

    // ---- loading rows, packed over state pairs: W2[kp][r] = {k=2kp, k=2kp+1} ----
    v2f WU2[4][8];   // alpha*U (f=8..15)
    v2f WV2[4][8];   // w*V     (f=16..23)
    v2f WO2[4][4];   // w*O     (f=24..27)

    #pragma unroll
    for (int pr = 0; pr < 4; ++pr) {       // one state pair at a time
        float nlr[2][NF];
        #pragma unroll
        for (int kk = 0; kk < 2; ++kk) {
            const float4* s4 = (const float4*)(nl + (size_t)(s0 + pr * 2 + kk) * NF);
            #pragma unroll
            for (int q = 0; q < 7; ++q) {
                float4 v = s4[q];
                nlr[kk][q*4+0] = v.x; nlr[kk][q*4+1] = v.y;
                nlr[kk][q*4+2] = v.z; nlr[kk][q*4+3] = v.w;
            }
        }
        #pragma unroll
        for (int f = 8; f < NF; ++f) {
            const float4* cr = (const float4*)&c_lds[(p * NF + f) * NF];
            float crow[NF];
            #pragma unroll
            for (int q = 0; q < 7; ++q) {
                float4 v = cr[q];
                crow[q*4+0] = v.x; crow[q*4+1] = v.y;
                crow[q*4+2] = v.z; crow[q*4+3] = v.w;
            }
            #pragma unroll
            for (int kk = 0; kk < 2; ++kk) {
                float acc = mu_lds[p * NF + f];
                #pragma unroll
                for (int ss = 0; ss < NF; ++ss)
                    acc = __builtin_fmaf(crow[ss], nlr[kk][ss], acc);
                if (f < 16)      WU2[pr][f - 8][kk]  = acc;
                else if (f < 24) WV2[pr][f - 16][kk] = acc;
                else             WO2[pr][f - 24][kk] = acc;
            }
        }
    }
    #pragma unroll
    for (int kp = 0; kp < 4; ++kp) {
        #pragma unroll
        for (int c = 0; c < 8; ++c) { WU2[kp][c] *= ALPHA; WV2[kp][c] *= w_p; }
        #pragma unroll
        for (int c = 0; c < 4; ++c) WO2[kp][c] *= w_p;
    }

    // ---- h init (packed), ext prefetch with scalar running pointer ----
    v2f h2[4];
    {
        const float4* hp = (const float4*)(h0 + s0);
        float4 v0 = hp[0], v1 = hp[1];
        h2[0] = mk2(v0.x, v0.y); h2[1] = mk2(v0.z, v0.w);
        h2[2] = mk2(v1.x, v1.y); h2[3] = mk2(v1.z, v1.w);
    }
    const size_t rowq = NSTATES / 4;
    const float4* nbase = (const float4*)ext + (size_t)b * (TSTEPS * NSTATES / 4) + tid * 2;
    float4 nA0 = nbase[0], nA1 = nbase[1];              // t=0
    float4 nB0 = nbase[rowq], nB1 = nbase[rowq + 1];    // t=1
    const float4* np = nbase + 2 * rowq;                // row t+2, advanced scalar-ly
    float* yout = y + (size_t)b * (TSTEPS + 1) * NO;

    const int s2addr = ((lane & 3) << 3) | (lane >> 3);

    auto STEP = [&](int t, float4& nc0, float4& nc1) {
        float4 u0 = nc0, u1 = nc1;
        nc0 = np[0]; nc1 = np[1];                   // prefetch t+2 (in flight across barrier)
        np += (t < TSTEPS - 3) ? rowq : 0;          // uniform: s_cselect + s_add

        // packed tanh
        v2f phi2[4];
        #pragma unroll
        for (int kp = 0; kp < 4; ++kp) phi2[kp] = ftanh2(h2[kp]);

        // kappa partials (8) + y partials (4): packed dot over 4 state pairs
        float red[12];
        #pragma unroll
        for (int r = 0; r < 8; ++r) {
            v2f a = phi2[0] * WV2[0][r];
            a = fma2(phi2[1], WV2[1][r], a);
            a = fma2(phi2[2], WV2[2][r], a);
            a = fma2(phi2[3], WV2[3][r], a);
            red[r] = a.x + a.y;
        }
        #pragma unroll
        for (int o = 0; o < 4; ++o) {
            v2f a = phi2[0] * WO2[0][o];
            a = fma2(phi2[1], WO2[1][o], a);
            a = fma2(phi2[2], WO2[2][o], a);
            a = fma2(phi2[3], WO2[3][o], a);
            red[8 + o] = a.x + a.y;
        }
        #pragma unroll
        for (int i = 0; i < 12; ++i) red[i] = wave_red_sum(red[i]);

        if (lane == 63) {
            *(float4*)&part[t & 1][wid][0] = float4{red[0], red[1], red[2], red[3]};
            *(float4*)&part[t & 1][wid][4] = float4{red[4], red[5], red[6], red[7]};
            *(float4*)&ybuf[t][wid][0]     = float4{red[8], red[9], red[10], red[11]};
        }

        // base = ONEMA*h + ext (packed)
        v2f base2[4];
        base2[0] = fma2(s2(ONEMA), h2[0], mk2(u0.x, u0.y));
        base2[1] = fma2(s2(ONEMA), h2[1], mk2(u0.z, u0.w));
        base2[2] = fma2(s2(ONEMA), h2[2], mk2(u1.x, u1.y));
        base2[3] = fma2(s2(ONEMA), h2[3], mk2(u1.z, u1.w));
        lds_barrier();

        // stage 2: broadcast ds_read + red4 + readlane -> kf in SGPRs
        float pv = (&part[t & 1][0][0])[s2addr];
        pv = red4(pv);
        float kf0 = readlane_f(pv, 3),  kf1 = readlane_f(pv, 11);
        float kf2 = readlane_f(pv, 19), kf3 = readlane_f(pv, 27);
        float kf4 = readlane_f(pv, 35), kf5 = readlane_f(pv, 43);
        float kf6 = readlane_f(pv, 51), kf7 = readlane_f(pv, 59);

        // packed update: h = base + U·kf (two 4-deep chains per pair)
        #pragma unroll
        for (int kp = 0; kp < 4; ++kp) {
            v2f a = fma2(s2(kf0), WU2[kp][0], base2[kp]);
            a = fma2(s2(kf1), WU2[kp][1], a);
            a = fma2(s2(kf2), WU2[kp][2], a);
            a = fma2(s2(kf3), WU2[kp][3], a);
            v2f c = s2(kf4) * WU2[kp][4];
            c = fma2(s2(kf5), WU2[kp][5], c);
            c = fma2(s2(kf6), WU2[kp][6], c);
            c = fma2(s2(kf7), WU2[kp][7], c);
            h2[kp] = a + c;
        }
    };

    for (int t = 0; t < TSTEPS; t += 2) {
        STEP(t,     nA0, nA1);
        STEP(t + 1, nB0, nB1);
    }

    // ---- final y partials from h_T ----
    {
        v2f phi2[4];
        #pragma unroll
        for (int kp = 0; kp < 4; ++kp) phi2[kp] = ftanh2(h2[kp]);
        float yred[4];
        #pragma unroll
        for (int o = 0; o < 4; ++o) {
            v2f a = phi2[0] * WO2[0][o];
            a = fma2(phi2[1], WO2[1][o], a);
            a = fma2(phi2[2], WO2[2][o], a);
            a = fma2(phi2[3], WO2[3][o], a);
            yred[o] = a.x + a.y;
        }
        #pragma unroll
        for (int o = 0; o < 4; ++o) yred[o] = wave_red_sum(yred[o]);
        if (lane == 63)
            *(float4*)&ybuf[TSTEPS][wid][0] = float4{yred[0], yred[1], yred[2], yred[3]};
    }
    lds_barrier();

    for (int idx = tid; idx < (TSTEPS + 1) * NO; idx += THREADS) {
        int t = idx >> 2, o = idx & 3;
        yout[idx] = (ybuf[t][0][o] + ybuf[t][1][o]) + (ybuf[t][2][o] + ybuf[t][3][o]);
    }
}

// =====================================================================
// Fallback (ws too small): R9-style fully-fused single-batch kernel.
// =====================================================================
__global__ __launch_bounds__(256, 1)
void rnn_fallback(
    const float* __restrict__ u, const float* __restrict__ G,
    const float* __restrict__ mu, const float* __restrict__ C,
    const float* __restrict__ h0, const float* __restrict__ nl,
    const float* __restrict__ nrec, float* __restrict__ y)
{
    __shared__ float u_lds[TSTEPS * NI];
    __shared__ float c_lds[NPOP * NF * NF];
    __shared__ float mu_lds[NPOP * NF];
    __shared__ __align__(16) float part[2][4][8];
    __shared__ __align__(16) float ybuf[TSTEPS + 1][4][4];

    const int tid  = threadIdx.x;
    const int b    = blockIdx.x;
    const int lane = tid & 63;
    const int wid  = tid >> 6;
    const int p    = wid;
    const int s0   = tid * SPT;

    {
        const float4* s4 = (const float4*)(u + (size_t)b * TSTEPS * NI);
        ((float4*)u_lds)[tid]       = s4[tid];
        ((float4*)u_lds)[tid + 256] = s4[tid + 256];
    }
    {
        const float4* s4 = (const float4*)C;
        float4* dst = (float4*)c_lds;
        #pragma unroll
        for (int i = 0; i < 4; ++i) {
            int idx = tid + i * 256;
            if (idx < NPOP * NF * NF / 4) dst[idx] = s4[idx];
        }
    }
    if (tid < NPOP * NF) mu_lds[tid] = mu[tid];

    float w_p;
    {
        float g0 = G[0], g1 = G[1], g2 = G[2], g3 = G[3];
        float mx = fmaxf(fmaxf(g0, g1), fmaxf(g2, g3));
        const float L2E = 1.4426950408889634f;
        float e0 = vexp2((g0 - mx) * L2E), e1 = vexp2((g1 - mx) * L2E);
        float e2 = vexp2((g2 - mx) * L2E), e3 = vexp2((g3 - mx) * L2E);
        float inv = vrcp(e0 + e1 + e2 + e3);
        float ap = (p == 0) ? e0 : (p == 1) ? e1 : (p == 2) ? e2 : e3;
        w_p = ap * inv * (1.0f / (float)RANDN);
    }
    __syncthreads();

    float W[SPT][NF];
    #pragma unroll
    for (int f = 0; f < NF; ++f) {
        float m = mu_lds[p * NF + f];
        #pragma unroll
        for (int k = 0; k < SPT; ++k) W[k][f] = m;
    }
    #pragma unroll
    for (int pr = 0; pr < 2; ++pr) {
        float nlr[4][NF];
        #pragma unroll
        for (int kk = 0; kk < 4; ++kk) {
            const float4* s4 = (const float4*)(nl + (size_t)(s0 + pr * 4 + kk) * NF);
            #pragma unroll
            for (int q = 0; q < 7; ++q) {
                float4 v = s4[q];
                nlr[kk][q*4+0] = v.x; nlr[kk][q*4+1] = v.y;
                nlr[kk][q*4+2] = v.z; nlr[kk][q*4+3] = v.w;
            }
        }
        #pragma unroll
        for (int f = 0; f < NF; ++f) {
            const float4* cr = (const float4*)&c_lds[(p * NF + f) * NF];
            float crow[NF];
            #pragma unroll
            for (int q = 0; q < 7; ++q) {
                float4 v = cr[q];
                crow[q*4+0] = v.x; crow[q*4+1] = v.y;
                crow[q*4+2] = v.z; crow[q*4+3] = v.w;
            }
            #pragma unroll
            for (int kk = 0; kk < 4; ++kk) {
                float acc = W[pr*4+kk][f];
                #pragma unroll
                for (int ss = 0; ss < NF; ++ss)
                    acc = __builtin_fmaf(crow[ss], nlr[kk][ss], acc);
                W[pr*4+kk][f] = acc;
            }
        }
    }
    #pragma unroll
    for (int k = 0; k < SPT; ++k) {
        #pragma unroll
        for (int f = 0; f < 16; ++f) W[k][f] *= ALPHA;
        #pragma unroll
        for (int f = 16; f < NF; ++f) W[k][f] *= w_p;
    }

    float h[SPT];
    {
        const float4* hp = (const float4*)(h0 + s0);
        float4 v0 = hp[0], v1 = hp[1];
        h[0]=v0.x; h[1]=v0.y; h[2]=v0.z; h[3]=v0.w;
        h[4]=v1.x; h[5]=v1.y; h[6]=v1.z; h[7]=v1.w;
    }
    const float4* nbase = (const float4*)nrec + (size_t)b * (TSTEPS * NSTATES / 4) + tid * 2;
    float4 nA0 = nbase[0], nA1 = nbase[1];
    float4 nB0 = nbase[NSTATES / 4], nB1 = nbase[NSTATES / 4 + 1];
    float* yout = y + (size_t)b * (TSTEPS + 1) * NO;
    const int s2addr = ((lane & 3) << 3) | (lane >> 3);

    auto STEP = [&](int t, float4& nc0, float4& nc1) {
        float4 u0 = nc0, u1 = nc1;
        int tp = (t + 2 < TSTEPS) ? (t + 2) : (TSTEPS - 1);
        nc0 = nbase[(size_t)tp * (NSTATES / 4)];
        nc1 = nbase[(size_t)tp * (NSTATES / 4) + 1];

        float phi[SPT];
        #pragma unroll
        for (int k = 0; k < SPT; ++k) phi[k] = ftanh(h[k]);

        float red[12];
        #pragma unroll
        for (int r = 0; r < 8; ++r) {
            float a = phi[0] * W[0][16 + r];
            #pragma unroll
            for (int k = 1; k < SPT; ++k) a = __builtin_fmaf(phi[k], W[k][16 + r], a);
            red[r] = a;
        }
        #pragma unroll
        for (int o = 0; o < 4; ++o) {
            float a = phi[0] * W[0][24 + o];
            #pragma unroll
            for (int k = 1; k < SPT; ++k) a = __builtin_fmaf(phi[k], W[k][24 + o], a);
            red[8 + o] = a;
        }
        #pragma unroll
        for (int i = 0; i < 12; ++i) red[i] = wave_red_sum(red[i]);

        if (lane == 63) {
            *(float4*)&part[t & 1][wid][0] = float4{red[0], red[1], red[2], red[3]};
            *(float4*)&part[t & 1][wid][4] = float4{red[4], red[5], red[6], red[7]};
            *(float4*)&ybuf[t][wid][0]     = float4{red[8], red[9], red[10], red[11]};
        }

        float ut[8];
        {
            const float4* up = (const float4*)&u_lds[t * NI];
            float4 a = up[0], bb = up[1];
            ut[0]=a.x; ut[1]=a.y; ut[2]=a.z; ut[3]=a.w;
            ut[4]=bb.x; ut[5]=bb.y; ut[6]=bb.z; ut[7]=bb.w;
        }
        float nn[8] = {u0.x, u0.y, u0.z, u0.w, u1.x, u1.y, u1.z, u1.w};
        float base[SPT];
        #pragma unroll
        for (int k = 0; k < SPT; ++k) {
            float acc0 = ALPHA * nn[k];
            #pragma unroll
            for (int i = 0; i < 4; ++i) acc0 = __builtin_fmaf(ut[i], W[k][i], acc0);
            float acc1 = ut[4] * W[k][4];
            #pragma unroll
            for (int i = 5; i < 8; ++i) acc1 = __builtin_fmaf(ut[i], W[k][i], acc1);
            base[k] = __builtin_fmaf(ONEMA, h[k], acc0 + acc1);
        }
        lds_barrier();

        float pv = (&part[t & 1][0][0])[s2addr];
        pv = red4(pv);
        float kf0 = readlane_f(pv, 3),  kf1 = readlane_f(pv, 11);
        float kf2 = readlane_f(pv, 19), kf3 = readlane_f(pv, 27);
        float kf4 = readlane_f(pv, 35), kf5 = readlane_f(pv, 43);
        float kf6 = readlane_f(pv, 51), kf7 = readlane_f(pv, 59);

        #pragma unroll
        for (int k = 0; k < SPT; ++k) {
            float r0 = kf0 * W[k][8];
            r0 = __builtin_fmaf(kf1, W[k][9],  r0);
            r0 = __builtin_fmaf(kf2, W[k][10], r0);
            r0 = __builtin_fmaf(kf3, W[k][11], r0);
            float r1 = kf4 * W[k][12];
            r1 = __builtin_fmaf(kf5, W[k][13], r1);
            r1 = __builtin_fmaf(kf6, W[k][14], r1);
            r1 = __builtin_fmaf(kf7, W[k][15], r1);
            h[k] = base[k] + (r0 + r1);
        }
    };

    for (int t = 0; t < TSTEPS; t += 2) {
        STEP(t,     nA0, nA1);
        STEP(t + 1, nB0, nB1);
    }

    {
        float phi[SPT];
        #pragma unroll
        for (int k = 0; k < SPT; ++k) phi[k] = ftanh(h[k]);
        float yred[4];
        #pragma unroll
        for (int o = 0; o < 4; ++o) {
            float a = phi[0] * W[0][24 + o];
            #pragma unroll
            for (int k = 1; k < SPT; ++k) a = __builtin_fmaf(phi[k], W[k][24 + o], a);
            yred[o] = a;
        }
        #pragma unroll
        for (int o = 0; o < 4; ++o) yred[o] = wave_red_sum(yred[o]);
        if (lane == 63)
            *(float4*)&ybuf[TSTEPS][wid][0] = float4{yred[0], yred[1], yred[2], yred[3]};
    }
    lds_barrier();

    for (int idx = tid; idx < (TSTEPS + 1) * NO; idx += 256) {
        int t = idx >> 2, o = idx & 3;
        yout[idx] = (ybuf[t][0][o] + ybuf[t][1][o]) + (ybuf[t][2][o] + ybuf[t][3][o]);
    }
}

extern "C" void kernel_launch(void* const* d_in, const int* in_sizes, int n_in,
                              void* d_out, int out_size, void* d_ws, size_t ws_size,
                              hipStream_t stream) {
    const float* u    = (const float*)d_in[0];
    const float* G    = (const float*)d_in[1];
    const float* mu   = (const float*)d_in[2];
    const float* C    = (const float*)d_in[3];
    const float* h0   = (const float*)d_in[4];
    const float* nl   = (const float*)d_in[5];
    const float* nrec = (const float*)d_in[6];
    float* yp = (float*)d_out;

    const size_t need = (size_t)NBATCH * TSTEPS * NSTATES * sizeof(float); // 128 MiB
    if (ws_size >= need) {
        float* ext = (float*)d_ws;
        ext_kernel<<<dim3(NBATCH * (TSTEPS / CHUNK)), dim3(256), 0, stream>>>(
            u, mu, C, nl, nrec, ext);
        rnn_fused<<<dim3(NBATCH), dim3(THREADS), 0, stream>>>(
            G, mu, C, h0, nl, ext, yp);
    } else {
        rnn_fallback<<<dim3(NBATCH), dim3(256), 0, stream>>>(
            u, G, mu, C, h0, nl, nrec, yp);
    }
}